// Round 5
// baseline (5351.405 us; speedup 1.0000x reference)
//
#include <hip/hip_runtime.h>
#include <math.h>

#define Bsz  8192
#define Mdim 512
#define Ndim 2048
#define Kit  16
#define Pk   50
#define EPSv 0.01f

typedef __attribute__((ext_vector_type(8))) short bf16x8;
typedef __attribute__((ext_vector_type(4))) float f32x4;

// ---- bf16 split helpers: x = h + l to ~2^-16 rel ---------------------------
static __device__ __forceinline__ unsigned short f2bf(float f) {
    unsigned u = __float_as_uint(f);
    return (unsigned short)((u + 0x7fffu + ((u >> 16) & 1u)) >> 16);  // RNE
}
static __device__ __forceinline__ float bf2f(unsigned short h) {
    return __uint_as_float(((unsigned)h) << 16);
}

// ---- async global->LDS, 16B per lane; LDS dest = uniform base + lane*16 ----
typedef __attribute__((address_space(1))) const unsigned gl_cu32;
typedef __attribute__((address_space(3))) unsigned lds_u32;
static __device__ __forceinline__ void dma16(const unsigned short* g, unsigned short* l) {
    __builtin_amdgcn_global_load_lds((gl_cu32*)g, (lds_u32*)l, 16, 0, 0);
}

// ---------------------------------------------------------------------------
// One-time: split A into bf16 planes Ah/Al [m][n] and AhT/AlT [n][m].
// ---------------------------------------------------------------------------
__global__ __launch_bounds__(256) void presplit_A(
    const float* __restrict__ A, unsigned short* __restrict__ Ah,
    unsigned short* __restrict__ Al, unsigned short* __restrict__ AhT,
    unsigned short* __restrict__ AlT)
{
    int idx = blockIdx.x * 256 + threadIdx.x;      // 0 .. M*N-1
    int m = idx >> 11, n = idx & (Ndim - 1);
    float a = A[idx];
    unsigned short h = f2bf(a);
    unsigned short l = f2bf(a - bf2f(h));
    Ah[idx] = h; Al[idx] = l;
    AhT[(size_t)n * Mdim + m] = h;
    AlT[(size_t)n * Mdim + m] = l;
}

// ---------------------------------------------------------------------------
// it=0: b = -y as h/l planes. b row layout: 512 h then 512 l (pitch 1024 us).
// ---------------------------------------------------------------------------
__global__ __launch_bounds__(256) void split_negy_kernel(const float* __restrict__ y,
                                                         unsigned short* __restrict__ bpl) {
    int gid = blockIdx.x * 256 + threadIdx.x;      // 8 elems per thread
    int row = gid >> 6;
    int col = (gid & 63) * 8;
    float4 v0 = *(const float4*)(y + (size_t)row * Mdim + col);
    float4 v1 = *(const float4*)(y + (size_t)row * Mdim + col + 4);
    float vv[8] = { -v0.x, -v0.y, -v0.z, -v0.w, -v1.x, -v1.y, -v1.z, -v1.w };
    unsigned short hs[8], ls[8];
#pragma unroll
    for (int e = 0; e < 8; e++) {
        hs[e] = f2bf(vv[e]);
        ls[e] = f2bf(vv[e] - bf2f(hs[e]));
    }
    uint4 hp = { (unsigned)hs[0] | ((unsigned)hs[1] << 16), (unsigned)hs[2] | ((unsigned)hs[3] << 16),
                 (unsigned)hs[4] | ((unsigned)hs[5] << 16), (unsigned)hs[6] | ((unsigned)hs[7] << 16) };
    uint4 lp = { (unsigned)ls[0] | ((unsigned)ls[1] << 16), (unsigned)ls[2] | ((unsigned)ls[3] << 16),
                 (unsigned)ls[4] | ((unsigned)ls[5] << 16), (unsigned)ls[6] | ((unsigned)ls[7] << 16) };
    unsigned short* bus = bpl + (size_t)row * 1024;
    *(uint4*)(bus + col)       = hp;
    *(uint4*)(bus + 512 + col) = lp;
}

// ---------------------------------------------------------------------------
// GEMM1 (NT): b[r][m] = sum_n z[r][n]*A[m][n] - y[r][m], out as h/l planes.
// z planes pitch 4096 us (h at +0, l at +2048). Tile 128(r)x64(m), BK=64.
// All operands DMA-staged; LDS [chunk][row][8] conflict-free.
// ---------------------------------------------------------------------------
__global__ __launch_bounds__(256) void gemm1_mfma(
    const unsigned short* __restrict__ zpl,
    const unsigned short* __restrict__ Ah, const unsigned short* __restrict__ Al,
    const float* __restrict__ y, unsigned short* __restrict__ bpl)
{
    const int tid  = threadIdx.x;
    const int lane = tid & 63, wid = tid >> 6;
    const int lm   = lane & 15, quad = lane >> 4;
    const int wr   = (wid & 1) * 64, wm = (wid >> 1) * 32;
    const int bid  = blockIdx.x;
    const int xcd  = bid & 7, tb = bid >> 3;
    const int m0   = (tb & 7) * 64;                 // 8 m-blocks share a strip
    const int r0   = ((xcd << 3) | (tb >> 3)) * 128; // strip -> one XCD

    __shared__ unsigned short zt[2][8][128][8];     // 32 KB
    __shared__ unsigned short at[2][8][64][8];      // 16 KB

    f32x4 acc[4][2];
#pragma unroll
    for (int i = 0; i < 4; i++)
#pragma unroll
        for (int j = 0; j < 2; j++) acc[i][j] = (f32x4)0.f;

    const unsigned short* gsrc;
    if (wid == 0)      gsrc = zpl + (size_t)(r0 + lane) * 4096;          // zh
    else if (wid == 1) gsrc = zpl + (size_t)(r0 + lane) * 4096 + 2048;   // zl
    else if (wid == 2) gsrc = Ah  + (size_t)(m0 + lane) * 2048;
    else               gsrc = Al  + (size_t)(m0 + lane) * 2048;

    for (int k0 = 0; k0 < Ndim; k0 += 64) {
        if (wid < 2) {
#pragma unroll
            for (int c = 0; c < 8; c++)
#pragma unroll
                for (int h = 0; h < 2; h++)
                    dma16(gsrc + (size_t)h * 64 * 4096 + k0 + c * 8,
                          &zt[wid][c][h * 64][0]);
        } else {
#pragma unroll
            for (int c = 0; c < 8; c++)
                dma16(gsrc + k0 + c * 8, &at[wid - 2][c][0][0]);
        }
        __syncthreads();   // drains vmcnt -> DMA data visible
#pragma unroll
        for (int kk = 0; kk < 2; kk++) {
            const int ck = kk * 4 + quad;
            bf16x8 bhf[2], blf[2];
#pragma unroll
            for (int fj = 0; fj < 2; fj++) {
                bhf[fj] = *(const bf16x8*)&at[0][ck][wm + fj * 16 + lm][0];
                blf[fj] = *(const bf16x8*)&at[1][ck][wm + fj * 16 + lm][0];
            }
#pragma unroll
            for (int fi = 0; fi < 4; fi++) {
                bf16x8 zh8 = *(const bf16x8*)&zt[0][ck][wr + fi * 16 + lm][0];
                bf16x8 zl8 = *(const bf16x8*)&zt[1][ck][wr + fi * 16 + lm][0];
#pragma unroll
                for (int fj = 0; fj < 2; fj++) {
                    acc[fi][fj] = __builtin_amdgcn_mfma_f32_16x16x32_bf16(zh8, bhf[fj], acc[fi][fj], 0, 0, 0);
                    acc[fi][fj] = __builtin_amdgcn_mfma_f32_16x16x32_bf16(zh8, blf[fj], acc[fi][fj], 0, 0, 0);
                    acc[fi][fj] = __builtin_amdgcn_mfma_f32_16x16x32_bf16(zl8, bhf[fj], acc[fi][fj], 0, 0, 0);
                }
            }
        }
        __syncthreads();   // WAR before next DMA overwrites LDS
    }
    // epilogue: b = acc - y, split, store h/l planes. D: col=lm, row=quad*4+r
#pragma unroll
    for (int fi = 0; fi < 4; fi++)
#pragma unroll
        for (int fj = 0; fj < 2; fj++)
#pragma unroll
            for (int r = 0; r < 4; r++) {
                int row = r0 + wr + fi * 16 + quad * 4 + r;
                int col = m0 + wm + fj * 16 + lm;
                float bv = acc[fi][fj][r] - y[(size_t)row * Mdim + col];
                unsigned short h = f2bf(bv);
                unsigned short l = f2bf(bv - bf2f(h));
                bpl[(size_t)row * 1024 + col]       = h;
                bpl[(size_t)row * 1024 + 512 + col] = l;
            }
}

// ---------------------------------------------------------------------------
// GEMM2 (NN): c[r][n] = sum_m b[r][m]*A[m][n], c fp32. b planes pitch 1024 us;
// A^T pre-split planes [n][m]. Tile 128x128, BK=32, all DMA-staged.
// ---------------------------------------------------------------------------
__global__ __launch_bounds__(256) void gemm2_mfma(
    const unsigned short* __restrict__ bpl,
    const unsigned short* __restrict__ AhT, const unsigned short* __restrict__ AlT,
    float* __restrict__ c)
{
    const int tid  = threadIdx.x;
    const int lane = tid & 63, wid = tid >> 6;
    const int lm   = lane & 15, quad = lane >> 4;
    const int wr   = (wid & 1) * 64, wn = (wid >> 1) * 64;
    const int bid  = blockIdx.x;
    const int xcd  = bid & 7, tb = bid >> 3;
    const int n0   = (tb & 15) * 128;                // 16 n-blocks share a strip
    const int r0   = ((xcd << 3) | (tb >> 4)) * 128; // strip -> one XCD

    __shared__ unsigned short bt[2][4][128][8];      // 16 KB
    __shared__ unsigned short att[2][4][128][8];     // 16 KB

    f32x4 acc[4][4];
#pragma unroll
    for (int i = 0; i < 4; i++)
#pragma unroll
        for (int j = 0; j < 4; j++) acc[i][j] = (f32x4)0.f;

    const unsigned short* gsrc;
    if (wid == 0)      gsrc = bpl + (size_t)(r0 + lane) * 1024;          // bh
    else if (wid == 1) gsrc = bpl + (size_t)(r0 + lane) * 1024 + 512;    // bl
    else if (wid == 2) gsrc = AhT + (size_t)(n0 + lane) * 512;
    else               gsrc = AlT + (size_t)(n0 + lane) * 512;

    const size_t rstep = (wid < 2) ? (size_t)64 * 1024 : (size_t)64 * 512;
    unsigned short (*dst)[128][8] = (wid == 0) ? bt[0] : (wid == 1) ? bt[1]
                                  : (wid == 2) ? att[0] : att[1];

    for (int k0 = 0; k0 < Mdim; k0 += 32) {
#pragma unroll
        for (int cc = 0; cc < 4; cc++)
#pragma unroll
            for (int h = 0; h < 2; h++)
                dma16(gsrc + rstep * h + k0 + cc * 8, &dst[cc][h * 64][0]);
        __syncthreads();
        {
            bf16x8 ahf[4], alf[4];
#pragma unroll
            for (int fj = 0; fj < 4; fj++) {
                ahf[fj] = *(const bf16x8*)&att[0][quad][wn + fj * 16 + lm][0];
                alf[fj] = *(const bf16x8*)&att[1][quad][wn + fj * 16 + lm][0];
            }
#pragma unroll
            for (int fi = 0; fi < 4; fi++) {
                bf16x8 bh8 = *(const bf16x8*)&bt[0][quad][wr + fi * 16 + lm][0];
                bf16x8 bl8 = *(const bf16x8*)&bt[1][quad][wr + fi * 16 + lm][0];
#pragma unroll
                for (int fj = 0; fj < 4; fj++) {
                    acc[fi][fj] = __builtin_amdgcn_mfma_f32_16x16x32_bf16(bh8, ahf[fj], acc[fi][fj], 0, 0, 0);
                    acc[fi][fj] = __builtin_amdgcn_mfma_f32_16x16x32_bf16(bh8, alf[fj], acc[fi][fj], 0, 0, 0);
                    acc[fi][fj] = __builtin_amdgcn_mfma_f32_16x16x32_bf16(bl8, ahf[fj], acc[fi][fj], 0, 0, 0);
                }
            }
        }
        __syncthreads();
    }
#pragma unroll
    for (int fi = 0; fi < 4; fi++)
#pragma unroll
        for (int fj = 0; fj < 4; fj++)
#pragma unroll
            for (int r = 0; r < 4; r++) {
                int row = r0 + wr + fi * 16 + quad * 4 + r;
                int col = n0 + wn + fj * 16 + lm;
                c[(size_t)row * Ndim + col] = acc[fi][fj][r];
            }
}

// ---------------------------------------------------------------------------
// Fused per-row: u = x - gamma*c; exact 50th-largest |u| (radix select);
// soft-threshold + overshoot; write x; write z as h/l bf16 planes in place
// of c (row layout: 2048 h then 2048 l, same 8 KB/row footprint).
// ---------------------------------------------------------------------------
__global__ __launch_bounds__(256) void topk_update_kernel(
    float* __restrict__ uz, float* __restrict__ x,
    const float* __restrict__ gamma, const float* __restrict__ theta,
    const float* __restrict__ a_param, const float* __restrict__ vv,
    const float* __restrict__ vu, int it)
{
    const int row = blockIdx.x;
    const int t   = threadIdx.x;
    float* crow = uz + (size_t)row * Ndim;
    float* xrow = x  + (size_t)row * Ndim;
    const float g = gamma[it];

    float4 c0 = *(const float4*)(crow + 8 * t);
    float4 c1 = *(const float4*)(crow + 8 * t + 4);
    float4 x0 = *(const float4*)(xrow + 8 * t);
    float4 x1 = *(const float4*)(xrow + 8 * t + 4);
    float cv[8] = { c0.x, c0.y, c0.z, c0.w, c1.x, c1.y, c1.z, c1.w };
    float xv[8] = { x0.x, x0.y, x0.z, x0.w, x1.x, x1.y, x1.z, x1.w };

    float uvals[8];
    unsigned keys[8];
#pragma unroll
    for (int e = 0; e < 8; e++) {
        uvals[e] = xv[e] - g * cv[e];
        keys[e]  = __float_as_uint(fabsf(uvals[e]));
    }

    __shared__ unsigned bins[256];
    __shared__ unsigned sel[2];

    unsigned prefix = 0;
    unsigned k = Pk;
#pragma unroll
    for (int pass = 0; pass < 4; ++pass) {
        const int shift = 24 - pass * 8;
        bins[t] = 0;
        __syncthreads();     // also orders all u/x loads before any z store
        const unsigned himask = (pass == 0) ? 0u : (0xFFFFFFFFu << (shift + 8));
#pragma unroll
        for (int e = 0; e < 8; e++) {
            if ((keys[e] & himask) == prefix)
                atomicAdd(&bins[(keys[e] >> shift) & 255], 1u);
        }
        __syncthreads();
        if (t < 64) {
            const int i0 = 255 - 4 * t;
            unsigned c0b = bins[i0], c1b = bins[i0 - 1];
            unsigned c2b = bins[i0 - 2], c3b = bins[i0 - 3];
            unsigned s = c0b + c1b + c2b + c3b;
            unsigned sc = s;
#pragma unroll
            for (int off = 1; off < 64; off <<= 1) {
                unsigned o = __shfl_up(sc, (unsigned)off);
                if (t >= off) sc += o;
            }
            unsigned pre = sc - s;
            unsigned cs[4] = { c0b, c1b, c2b, c3b };
#pragma unroll
            for (int j = 0; j < 4; j++) {
                unsigned cb = cs[j];
                if (pre < k && pre + cb >= k) { sel[0] = (unsigned)(i0 - j); sel[1] = k - pre; }
                pre += cb;
            }
        }
        __syncthreads();
        prefix |= sel[0] << shift;
        k = sel[1];
    }
    const float thresh = __uint_as_float(prefix);

    const float th = theta[it];
    const float ap = a_param[it];
    const bool haveNext = (it + 1) < Kit;
    float tn = 0.f, vn = 0.f, vun = 0.f;
    if (haveNext) { tn = theta[it + 1]; vn = vv[it + 1]; vun = vu[it + 1]; }

    float xo[8];
    unsigned short zh[8], zl[8];
#pragma unroll
    for (int e = 0; e < 8; e++) {
        float uval = uvals[e];
        float au   = fabsf(uval);
        bool keep  = au > thresh;
        float shr  = copysignf(fmaxf(au - th, 0.f), uval);
        float xn   = keep ? uval : shr;
        float d    = xn - xv[e];
        float ov   = 1.f + ap / (fabsf(d) + EPSv);
        float xr   = xv[e] + ov * d;
        xo[e] = xr;
        float z = (1.f + tn * vun * __expf(-vn * fabsf(xr))) * xr;
        zh[e] = f2bf(z);
        zl[e] = f2bf(z - bf2f(zh[e]));
    }
    float4 a0 = { xo[0], xo[1], xo[2], xo[3] };
    float4 a1 = { xo[4], xo[5], xo[6], xo[7] };
    *(float4*)(xrow + 8 * t)     = a0;
    *(float4*)(xrow + 8 * t + 4) = a1;
    if (haveNext) {
        uint4 hp = { (unsigned)zh[0] | ((unsigned)zh[1] << 16), (unsigned)zh[2] | ((unsigned)zh[3] << 16),
                     (unsigned)zh[4] | ((unsigned)zh[5] << 16), (unsigned)zh[6] | ((unsigned)zh[7] << 16) };
        uint4 lp = { (unsigned)zl[0] | ((unsigned)zl[1] << 16), (unsigned)zl[2] | ((unsigned)zl[3] << 16),
                     (unsigned)zl[4] | ((unsigned)zl[5] << 16), (unsigned)zl[6] | ((unsigned)zl[7] << 16) };
        unsigned short* zus = (unsigned short*)uz + (size_t)row * 4096;
        *(uint4*)(zus + 8 * t)        = hp;
        *(uint4*)(zus + 2048 + 8 * t) = lp;
    }
}

// ---------------------------------------------------------------------------
extern "C" void kernel_launch(void* const* d_in, const int* in_sizes, int n_in,
                              void* d_out, int out_size, void* d_ws, size_t ws_size,
                              hipStream_t stream) {
    const float* y       = (const float*)d_in[0];   // (B,M)
    const float* A       = (const float*)d_in[1];   // (M,N)
    const float* gamma   = (const float*)d_in[2];
    const float* theta   = (const float*)d_in[3];
    const float* a_param = (const float*)d_in[4];
    const float* v       = (const float*)d_in[5];
    const float* vu      = (const float*)d_in[6];
    // d_in[7] theta_init (unused: multiplies x==0), d_in[8] info (unused)

    float* x = (float*)d_out;                       // (B,N) + 2K zeros

    // workspace layout (88 MB total, same as R4)
    char* ws = (char*)d_ws;
    float*          uz  = (float*)ws;                                   // 64 MB: c fp32 / z h+l planes
    unsigned short* bpl = (unsigned short*)(ws + (size_t)Bsz * Ndim * 4); // 16 MB: b h+l planes
    unsigned short* Ah  = (unsigned short*)(ws + (size_t)80 * 1024 * 1024);
    unsigned short* Al  = Ah  + (size_t)Mdim * Ndim;                    // 2 MB each
    unsigned short* AhT = Al  + (size_t)Mdim * Ndim;
    unsigned short* AlT = AhT + (size_t)Mdim * Ndim;

    hipMemsetAsync(d_out, 0, (size_t)out_size * sizeof(float), stream);

    dim3 blk(256);

    presplit_A<<<(Mdim * Ndim) / 256, blk, 0, stream>>>(A, Ah, Al, AhT, AlT);
    split_negy_kernel<<<(Bsz * Mdim / 8) / 256, blk, 0, stream>>>(y, bpl);

    for (int it = 0; it < Kit; ++it) {
        if (it > 0)
            gemm1_mfma<<<512, blk, 0, stream>>>((const unsigned short*)uz, Ah, Al, y, bpl);
        gemm2_mfma<<<1024, blk, 0, stream>>>(bpl, AhT, AlT, uz);
        topk_update_kernel<<<Bsz, blk, 0, stream>>>(uz, x, gamma, theta, a_param, v, vu, it);
    }
}